// Round 5
// baseline (825.142 us; speedup 1.0000x reference)
//
#include <hip/hip_runtime.h>
#include <hip/hip_bf16.h>
#include <math.h>

#define NEG 0.1f

typedef __attribute__((ext_vector_type(8))) short short8;
typedef __attribute__((ext_vector_type(4))) float f32x4;

__device__ __forceinline__ float lrelu(float x){ return x >= 0.f ? x : NEG*x; }

// fp32x2 -> packed bf16x2 (RTNE)
__device__ __forceinline__ unsigned pk2(float lo, float hi){
    __hip_bfloat162 h = __float22bfloat162_rn(make_float2(lo, hi));
    union { __hip_bfloat162 h2; unsigned u; } cv; cv.h2 = h;
    return cv.u;
}
__device__ __forceinline__ float bflo(unsigned u){ return __uint_as_float(u << 16); }
__device__ __forceinline__ float bfhi(unsigned u){ return __uint_as_float(u & 0xFFFF0000u); }

// ---- prepass: w_in (512x256 fp32) -> bf16 row-major ----
__global__ __launch_bounds__(256) void k_wprep(const float* __restrict__ w_in, unsigned* __restrict__ wbf_u){
    int idx8 = (blockIdx.x*256 + threadIdx.x)*8;
    float4 v0 = *(const float4*)&w_in[idx8];
    float4 v1 = *(const float4*)&w_in[idx8+4];
    uint4 d;
    d.x = pk2(v0.x, v0.y); d.y = pk2(v0.z, v0.w);
    d.z = pk2(v1.x, v1.y); d.w = pk2(v1.z, v1.w);
    *(uint4*)&wbf_u[idx8>>1] = d;
}

// ---- pool1: input1 (8,512,128,128) -> p1t bf16 (b,n,c); no LDS, float2 loads ----
__global__ __launch_bounds__(256) void k_pool1(const float* __restrict__ in1, unsigned* __restrict__ p1u){
    const int y = blockIdx.x, cg = blockIdx.y, b = blockIdx.z;
    const int tid = threadIdx.x;
    const int x = tid & 63, w = tid >> 6;
    const int cbase = cg*32 + w*8;
    const float2* iv = (const float2*)in1;
    float out[8];
    #pragma unroll
    for (int j = 0; j < 8; ++j){
        int c = cbase + j;
        size_t r0 = (size_t)(b*512 + c)*8192 + (2*y)*64 + x;
        float2 a = iv[r0];
        float2 bb = iv[r0 + 64];
        float m = fmaxf(fmaxf(a.x,a.y), fmaxf(bb.x,bb.y));
        out[j] = m + (a.x+a.y+bb.x+bb.y)*0.25f;
    }
    uint4 d;
    d.x = pk2(out[0],out[1]); d.y = pk2(out[2],out[3]);
    d.z = pk2(out[4],out[5]); d.w = pk2(out[6],out[7]);
    int n = y*64 + x;
    *(uint4*)&p1u[(size_t)(b*4096 + n)*256 + cg*16 + w*4] = d;
}

// ---- fused 1x1 conv + bias + 2x2 max+mean pool via bf16 MFMA -> p2t bf16 (b,n,c) ----
// Block: 64 pixels (2 rows x 32 cols) x ALL 512 o; full K=256 B-tile resident in LDS.
// in2 is read exactly ONCE (536 MB total). A restaged per (o-chunk, kb) from L2-hot wbf.
__global__ __launch_bounds__(256) void k_convpool(const float* __restrict__ in2, const unsigned* __restrict__ wbf_u,
                                                  const float* __restrict__ b_in, unsigned* __restrict__ p2u){
    __shared__ unsigned Bs[64*128];   // 64 px x 256 k bf16, px stride 128 uints, swizzle on (px&7)
    __shared__ unsigned As[128*32];   // 128 o x 64 k bf16 per stage; epilogue reuses as float[128][17]
    const int b = blockIdx.y;
    const int Y = blockIdx.x >> 2, X = blockIdx.x & 3;
    const int tid = threadIdx.x;
    const int lane = tid & 63, w = tid >> 6;
    const int col = lane & 15, q = lane >> 4;

    // ---- stage Bs: in2 tile (2 rows x 32 cols x 256 k), register transpose ----
    {
        const int c8 = tid & 7, r = (tid>>3) & 1, kg = tid >> 4;   // kg 0..15
        #pragma unroll
        for (int j = 0; j < 2; ++j){
            float v[8][4];
            #pragma unroll
            for (int kk = 0; kk < 8; ++kk){
                int k = kg*16 + j*8 + kk;
                float4 t = *(const float4*)&in2[((size_t)(b*256 + k)*128 + 2*Y + r)*128 + X*32 + c8*4];
                v[kk][0]=t.x; v[kk][1]=t.y; v[kk][2]=t.z; v[kk][3]=t.w;
            }
            int g = kg*2 + j;
            #pragma unroll
            for (int i = 0; i < 4; ++i){
                int px = r*32 + c8*4 + i;
                uint4 d;
                d.x = pk2(v[0][i], v[1][i]); d.y = pk2(v[2][i], v[3][i]);
                d.z = pk2(v[4][i], v[5][i]); d.w = pk2(v[6][i], v[7][i]);
                *(uint4*)&Bs[px*128 + ((g ^ (px & 7)) << 2)] = d;
            }
        }
    }

    const int a_o8 = tid >> 3, a_kg = tid & 7;
    const int u6 = tid & 63, pq = tid >> 6;

    for (int o0 = 0; o0 < 4; ++o0){
        f32x4 acc[2][4];
        #pragma unroll
        for (int mt=0; mt<2; ++mt)
            #pragma unroll
            for (int nt=0; nt<4; ++nt) acc[mt][nt] = (f32x4){0.f,0.f,0.f,0.f};

        for (int kb = 0; kb < 4; ++kb){
            __syncthreads();   // protect As reuse (and Bs visibility on first pass)
            #pragma unroll
            for (int pass=0; pass<4; ++pass){
                int o = pass*32 + a_o8;
                uint4 d = *(const uint4*)&wbf_u[((size_t)(o0*128+o)*256 + kb*64 + a_kg*8) >> 1];
                *(uint4*)&As[o*32 + ((a_kg ^ ((o>>1)&7))<<2)] = d;
            }
            __syncthreads();
            #pragma unroll
            for (int ks=0; ks<2; ++ks){
                short8 af[2], bf[4];
                #pragma unroll
                for (int mt=0; mt<2; ++mt){
                    int m = w*32 + mt*16 + col;
                    af[mt] = *(const short8*)&As[m*32 + (((ks*4+q) ^ ((m>>1)&7))<<2)];
                }
                int g = kb*8 + ks*4 + q;
                #pragma unroll
                for (int nt=0; nt<4; ++nt){
                    int px = nt*16 + col;
                    bf[nt] = *(const short8*)&Bs[px*128 + ((g ^ (px & 7))<<2)];
                }
                #pragma unroll
                for (int mt=0; mt<2; ++mt)
                    #pragma unroll
                    for (int nt=0; nt<4; ++nt)
                        acc[mt][nt] = __builtin_amdgcn_mfma_f32_16x16x32_bf16(af[mt], bf[nt], acc[mt][nt], 0,0,0);
            }
        }
        __syncthreads();
        // ---- 2x2 pool: row pairs = (nt, nt+2); col pairs via shfl_xor(1) ----
        float* outs = (float*)As;   // 128 o x 16 p, stride 17
        #pragma unroll
        for (int mt=0; mt<2; ++mt){
            #pragma unroll
            for (int ntp=0; ntp<2; ++ntp){
                #pragma unroll
                for (int reg=0; reg<4; ++reg){
                    float a = acc[mt][ntp][reg], bb = acc[mt][ntp+2][reg];
                    float mx = fmaxf(a, bb), sm = a + bb;
                    float mx2 = fmaxf(mx, __shfl_xor(mx, 1));
                    float sm2 = sm + __shfl_xor(sm, 1);
                    if ((lane & 1) == 0){
                        int p = ntp*8 + (col>>1);
                        int o = w*32 + mt*16 + q*4 + reg;
                        outs[o*17 + p] = mx2 + sm2*0.25f;
                    }
                }
            }
        }
        __syncthreads();
        // ---- pack + coalesced store: 128 c x 16 px for this o-chunk ----
        #pragma unroll
        for (int i = 0; i < 4; ++i){
            int p = pq*4 + i;
            int n = Y*64 + X*16 + p;
            float vlo = outs[(u6*2  )*17 + p] + 2.0f*b_in[o0*128 + u6*2];
            float vhi = outs[(u6*2+1)*17 + p] + 2.0f*b_in[o0*128 + u6*2+1];
            p2u[(size_t)(b*4096 + n)*256 + o0*64 + u6] = pk2(vlo, vhi);
        }
    }
}

// ---- rows: q=focus(lrelu(p1+pos1)/spl) in-place bf16; k likewise -> kfoc. 2 rows/block ----
__global__ __launch_bounds__(256) void k_rows(unsigned* __restrict__ p1u, const unsigned* __restrict__ p2u,
                                              const float* __restrict__ pos1, const float* __restrict__ pos2,
                                              const float* __restrict__ scale_param, unsigned* __restrict__ kfu){
    const int b = blockIdx.y;
    const int tid = threadIdx.x;
    const int half = tid >> 7, t = tid & 127;
    const int n = blockIdx.x*2 + half;
    const int c0 = t*4;
    const size_t base2 = (size_t)(b*4096 + n)*128;   // uint2 index
    __shared__ float red[4][4];
    uint2 u1 = *(const uint2*)&p1u[base2*2 + t*2];
    uint2 u2 = *(const uint2*)&p2u[base2*2 + t*2];
    float4 po1 = *(const float4*)&pos1[n*512 + c0];
    float4 po2 = *(const float4*)&pos2[n*512 + c0];
    float4 scv = *(const float4*)&scale_param[c0];
    float qv[4], kv_[4];
    float pq2=0.f, pq6=0.f, pk2_=0.f, pk6=0.f;
    {
        float p1a[4] = {bflo(u1.x), bfhi(u1.x), bflo(u1.y), bfhi(u1.y)};
        float p2a[4] = {bflo(u2.x), bfhi(u2.x), bflo(u2.y), bfhi(u2.y)};
        float poa1[4] = {po1.x,po1.y,po1.z,po1.w};
        float poa2[4] = {po2.x,po2.y,po2.z,po2.w};
        float sca[4] = {scv.x,scv.y,scv.z,scv.w};
        #pragma unroll
        for (int j = 0; j < 4; ++j){
            float sp = sca[j];
            float inv = 1.0f/(fmaxf(sp,0.f) + log1pf(expf(-fabsf(sp))));
            float qq = lrelu(p1a[j] + poa1[j]) * inv;
            float kk = lrelu(p2a[j] + poa2[j]) * inv;
            qv[j]=qq; kv_[j]=kk;
            float a;
            a = qq*qq; pq2 += a; pq6 += a*a*a;
            a = kk*kk; pk2_ += a; pk6 += a*a*a;
        }
    }
    #pragma unroll
    for (int off = 32; off > 0; off >>= 1){
        pq2 += __shfl_xor(pq2, off);
        pq6 += __shfl_xor(pq6, off);
        pk2_ += __shfl_xor(pk2_, off);
        pk6 += __shfl_xor(pk6, off);
    }
    int wave = tid >> 6;
    if ((tid & 63) == 0){ red[wave][0]=pq2; red[wave][1]=pq6; red[wave][2]=pk2_; red[wave][3]=pk6; }
    __syncthreads();
    float sq2 = red[2*half][0]+red[2*half+1][0];
    float sq6 = red[2*half][1]+red[2*half+1][1];
    float sk2 = red[2*half][2]+red[2*half+1][2];
    float sk6 = red[2*half][3]+red[2*half+1][3];
    float fq = sqrtf(sq2/sq6);
    float fk = sqrtf(sk2/sk6);
    uint2 dq, dk;
    dq.x = pk2(qv[0]*qv[0]*qv[0]*fq, qv[1]*qv[1]*qv[1]*fq);
    dq.y = pk2(qv[2]*qv[2]*qv[2]*fq, qv[3]*qv[3]*qv[3]*fq);
    dk.x = pk2(kv_[0]*kv_[0]*kv_[0]*fk, kv_[1]*kv_[1]*kv_[1]*fk);
    dk.y = pk2(kv_[2]*kv_[2]*kv_[2]*fk, kv_[3]*kv_[3]*kv_[3]*fk);
    *(uint2*)&p1u[base2*2 + t*2] = dq;
    *(uint2*)&kfu[base2*2 + t*2] = dk;
}

// ---- kv[b,h,d,e] = sum_n k*v / N ; one barrier, packed-bf16 LDS stage ----
__global__ __launch_bounds__(256) void k_kv(const unsigned* __restrict__ kfu, const unsigned* __restrict__ p2u,
                                            float* __restrict__ kv){
    __shared__ unsigned ksu[4096], vsu[4096];
    const int nc = blockIdx.x, h = blockIdx.y, b = blockIdx.z;
    const int tid = threadIdx.x;
    #pragma unroll
    for (int it = 0; it < 16; ++it){
        int i = it*256 + tid;
        int n = i >> 4, u = i & 15;
        size_t g = (size_t)(b*4096 + nc*256 + n)*256 + h*16 + u;
        ksu[i] = kfu[g];
        vsu[i] = p2u[g];
    }
    __syncthreads();
    const int d = tid >> 3, e2 = (tid & 7)*2;
    const unsigned kmaskhi = (d & 1) ? 1u : 0u;
    float acc[4] = {0.f,0.f,0.f,0.f};
    #pragma unroll 8
    for (int n = 0; n < 256; ++n){
        unsigned ku = ksu[n*16 + (d>>1)];
        float kd = kmaskhi ? bfhi(ku) : bflo(ku);
        uint2 vv = *(const uint2*)&vsu[n*16 + e2];
        acc[0] += kd*bflo(vv.x); acc[1] += kd*bfhi(vv.x);
        acc[2] += kd*bflo(vv.y); acc[3] += kd*bfhi(vv.y);
    }
    float* dst = &kv[((size_t)(b*16 + h)*32 + d)*32 + (tid&7)*4];
    const float sc = 1.0f/4096.0f;
    atomicAdd(dst+0, acc[0]*sc);
    atomicAdd(dst+1, acc[1]*sc);
    atomicAdd(dst+2, acc[2]*sc);
    atomicAdd(dst+3, acc[3]*sc);
}

// ---- attn: x = q.kv + lrelu(v.w_v^T + b_v); output (b,c,n) bf16 ----
__global__ __launch_bounds__(256) void k_attn(const unsigned* __restrict__ qfu, const unsigned* __restrict__ p2u,
                                              const float* __restrict__ kv, const float* __restrict__ w_v,
                                              const float* __restrict__ b_v, unsigned short* __restrict__ attn){
    __shared__ float kvs[1024];
    __shared__ float wvsT[32*36];
    __shared__ float qsl[64*32];
    __shared__ float vsl[64*32];
    __shared__ float to[32*66];
    const int nt = blockIdx.x, h = blockIdx.y, b = blockIdx.z;
    const int tid = threadIdx.x;
    #pragma unroll
    for (int it = 0; it < 4; ++it){
        int i = it*256 + tid;
        kvs[i] = kv[(size_t)(b*16 + h)*1024 + i];
        int e_ = i >> 5, d_ = i & 31;
        wvsT[d_*36 + e_] = w_v[e_*32 + d_];
    }
    #pragma unroll
    for (int it = 0; it < 4; ++it){
        int i = it*256 + tid;
        int nn = i >> 4, cp = i & 15;
        size_t g = (size_t)(b*4096 + nt*64 + nn)*256 + h*16 + cp;
        unsigned qu = qfu[g], vu = p2u[g];
        qsl[nn*32 + cp*2]   = bflo(qu);
        qsl[nn*32 + cp*2+1] = bfhi(qu);
        vsl[nn*32 + cp*2]   = bflo(vu);
        vsl[nn*32 + cp*2+1] = bfhi(vu);
    }
    __syncthreads();
    const int e0 = (tid & 7)*4, ng = tid >> 3;
    float4 bv = make_float4(b_v[e0], b_v[e0+1], b_v[e0+2], b_v[e0+3]);
    #pragma unroll
    for (int half = 0; half < 2; ++half){
        int nn = ng + half*32;
        float xa[4] = {0.f,0.f,0.f,0.f}, va[4] = {0.f,0.f,0.f,0.f};
        #pragma unroll
        for (int dq = 0; dq < 8; ++dq){
            float4 q4 = *(const float4*)&qsl[nn*32 + dq*4];
            float4 v4 = *(const float4*)&vsl[nn*32 + dq*4];
            float qarr[4] = {q4.x,q4.y,q4.z,q4.w};
            float varr[4] = {v4.x,v4.y,v4.z,v4.w};
            #pragma unroll
            for (int l = 0; l < 4; ++l){
                int d = dq*4 + l;
                float4 kvv = *(const float4*)&kvs[d*32 + e0];
                float4 wvv = *(const float4*)&wvsT[d*36 + e0];
                xa[0] += qarr[l]*kvv.x; xa[1] += qarr[l]*kvv.y; xa[2] += qarr[l]*kvv.z; xa[3] += qarr[l]*kvv.w;
                va[0] += varr[l]*wvv.x; va[1] += varr[l]*wvv.y; va[2] += varr[l]*wvv.z; va[3] += varr[l]*wvv.w;
            }
        }
        to[(e0+0)*66 + nn] = xa[0] + lrelu(va[0] + bv.x);
        to[(e0+1)*66 + nn] = xa[1] + lrelu(va[1] + bv.y);
        to[(e0+2)*66 + nn] = xa[2] + lrelu(va[2] + bv.z);
        to[(e0+3)*66 + nn] = xa[3] + lrelu(va[3] + bv.w);
    }
    __syncthreads();
    const int cc = tid >> 3, n0 = (tid & 7)*8;
    uint4 d;
    d.x = pk2(to[cc*66+n0+0], to[cc*66+n0+1]);
    d.y = pk2(to[cc*66+n0+2], to[cc*66+n0+3]);
    d.z = pk2(to[cc*66+n0+4], to[cc*66+n0+5]);
    d.w = pk2(to[cc*66+n0+6], to[cc*66+n0+7]);
    *(uint4*)&attn[((size_t)(b*512) + h*32 + cc)*4096 + nt*64 + n0] = d;
}

// ---- bilinear 64->128 align_corners + sigmoid; attn bf16 (b,c,n) -> out fp32 ----
__global__ __launch_bounds__(256) void k_up(const unsigned* __restrict__ attn_u, float* __restrict__ out){
    __shared__ float sA[18*65];
    const int qy = blockIdx.x;            // 0..3
    const int bc = blockIdx.y;            // 0..4095
    const int tid = threadIdx.x;
    const int ybase = (qy*32*63)/127;     // 0,15,31,47
    const size_t sb = (size_t)bc*2048;    // uints per bc slice
    for (int i = tid; i < 576; i += 256){
        int r = i >> 5, cu = i & 31;
        int ridx = ybase + r; if (ridx > 63) ridx = 63;
        unsigned u = attn_u[sb + ridx*32 + cu];
        sA[r*65 + cu*2]   = bflo(u);
        sA[r*65 + cu*2+1] = bfhi(u);
    }
    __syncthreads();
    const float rr = 63.0f/127.0f;
    const int ro = tid >> 3, cbase = tid & 7;
    const int yo = qy*32 + ro;
    float ty = yo * rr;
    int y0 = (int)ty; y0 = y0 > 62 ? 62 : y0;
    float wy = ty - (float)y0;
    const float* ra = &sA[(y0 - ybase)*65];
    const float* rb = ra + 65;
    float* orow = &out[((size_t)bc*128 + yo)*128];
    #pragma unroll
    for (int t = 0; t < 4; ++t){
        int xo0 = (cbase + t*8)*4;
        float4 o;
        float* op = (float*)&o;
        #pragma unroll
        for (int j = 0; j < 4; ++j){
            int xo = xo0 + j;
            float tx = xo * rr;
            int x0 = (int)tx; x0 = x0 > 62 ? 62 : x0;
            float wx = tx - (float)x0;
            float a00 = ra[x0], a01 = ra[x0+1];
            float a10 = rb[x0], a11 = rb[x0+1];
            float v = (a00*(1.f-wy) + a10*wy)*(1.f-wx) + (a01*(1.f-wy) + a11*wy)*wx;
            op[j] = 1.0f/(1.0f + expf(-v));
        }
        *(float4*)&orow[xo0] = o;
    }
}

extern "C" void kernel_launch(void* const* d_in, const int* in_sizes, int n_in,
                              void* d_out, int out_size, void* d_ws, size_t ws_size,
                              hipStream_t stream){
    const float* in1  = (const float*)d_in[0];
    const float* in2  = (const float*)d_in[1];
    const float* w_in = (const float*)d_in[2];
    const float* b_in = (const float*)d_in[3];
    const float* w_v  = (const float*)d_in[4];
    const float* b_v  = (const float*)d_in[5];
    const float* scp  = (const float*)d_in[6];
    const float* pos1 = (const float*)d_in[7];
    const float* pos2 = (const float*)d_in[8];
    float* out = (float*)d_out;
    char* ws  = (char*)d_ws;

    const size_t PBYTES = (size_t)8*4096*512*2;   // 33.55 MB per bf16 (b,n,c) buffer
    unsigned short* p1t  = (unsigned short*)ws;                 // qfoc in-place after k_rows
    unsigned short* p2t  = (unsigned short*)(ws + PBYTES);      // pooled projected input2 == v
    unsigned short* kfoc = (unsigned short*)(ws + 2*PBYTES);    // focused k; reused as attn (b,c,n)
    float*          kvb  = (float*)(ws + 3*PBYTES);             // 512 KB
    unsigned*       wbf  = (unsigned*)(ws + 3*PBYTES + (size_t)8*16*32*32*4);  // 256 KB bf16 w_in

    hipMemsetAsync(kvb, 0, (size_t)8*16*32*32*sizeof(float), stream);
    k_wprep   <<<64,            256, 0, stream>>>(w_in, wbf);
    k_pool1   <<<dim3(64,16,8), 256, 0, stream>>>(in1, (unsigned*)p1t);
    k_convpool<<<dim3(256,8),   256, 0, stream>>>(in2, wbf, b_in, (unsigned*)p2t);
    k_rows    <<<dim3(2048,8),  256, 0, stream>>>((unsigned*)p1t, (const unsigned*)p2t, pos1, pos2, scp, (unsigned*)kfoc);
    k_kv      <<<dim3(16,16,8), 256, 0, stream>>>((const unsigned*)kfoc, (const unsigned*)p2t, kvb);
    k_attn    <<<dim3(64,16,8), 256, 0, stream>>>((const unsigned*)p1t, (const unsigned*)p2t, kvb, w_v, b_v, kfoc);
    k_up      <<<dim3(4,4096),  256, 0, stream>>>((const unsigned*)kfoc, out);
}